// Round 2
// baseline (808.697 us; speedup 1.0000x reference)
//
#include <hip/hip_runtime.h>
#include <math.h>

// Problem constants (from reference)
#define BB    8
#define HMC   2
#define HH    152
#define WWW   272
#define HW    (HH * WWW)      // 41344
#define EMBD  128
#define KOBJ  128
#define KG    8192
#define NID0  500
#define NID1  300
#define TE    16              // entries per block in reid logits kernel

// d_ws layout (words):
//   [0] pos_loss [1] neg_loss [2] num_pos [3] num_wh [4] num_off [5] mask_sum
//   [6] nll0 [7] nll1   (float accumulators)
//   [8] cnt0 [9] cnt1   (int)
//   [16 .. 16+KG)            idx0 (int)
//   [16+KG .. 16+2KG)        idx1 (int)
//   [16+2KG .. 16+3KG)       tgt0 (int)
//   [16+3KG .. 16+4KG)       tgt1 (int)
//   [16+4KG ..)              emb0 (KG*128 f32) then emb1 (KG*128 f32)
// total ≈ 8.5 MB << ws_size (~677 MB observed)

__device__ __forceinline__ float wave_sum(float v) {
    #pragma unroll
    for (int o = 32; o > 0; o >>= 1) v += __shfl_down(v, o, 64);
    return v;
}

// ---------------- focal loss over hm_pred / hm ----------------
__global__ void focal_kernel(const float4* __restrict__ hp,
                             const float4* __restrict__ gt,
                             float* __restrict__ ws, int n4) {
    float pos = 0.f, neg = 0.f, cnt = 0.f;
    int stride = gridDim.x * blockDim.x;
    for (int i = blockIdx.x * blockDim.x + threadIdx.x; i < n4; i += stride) {
        float4 x = hp[i];
        float4 g = gt[i];
        float xs[4] = {x.x, x.y, x.z, x.w};
        float gs[4] = {g.x, g.y, g.z, g.w};
        #pragma unroll
        for (int j = 0; j < 4; ++j) {
            float s = 1.f / (1.f + expf(-xs[j]));
            s = fminf(fmaxf(s, 1e-4f), 1.f - 1e-4f);
            float gv = gs[j];
            if (gv == 1.f) {
                float om = 1.f - s;
                pos += logf(s) * om * om;
                cnt += 1.f;
            } else {
                float nw = 1.f - gv; nw = nw * nw; nw = nw * nw;
                neg += logf(1.f - s) * s * s * nw;
            }
        }
    }
    __shared__ float sm[3][4];
    float a = wave_sum(pos), b = wave_sum(neg), c = wave_sum(cnt);
    int lane = threadIdx.x & 63, wid = threadIdx.x >> 6;
    if (lane == 0) { sm[0][wid] = a; sm[1][wid] = b; sm[2][wid] = c; }
    __syncthreads();
    if (threadIdx.x == 0) {
        float s0 = 0, s1 = 0, s2 = 0;
        for (int w = 0; w < 4; ++w) { s0 += sm[0][w]; s1 += sm[1][w]; s2 += sm[2][w]; }
        atomicAdd(ws + 0, s0);
        atomicAdd(ws + 1, s1);
        atomicAdd(ws + 2, s2);
    }
}

// ---------------- wh / off L1 losses (single block) ----------------
__global__ void reg_kernel(const float* __restrict__ wh_pred,
                           const float* __restrict__ reg_pred,
                           const float* __restrict__ wh,
                           const float* __restrict__ reg,
                           const float* __restrict__ mask,
                           const int*   __restrict__ ind,
                           float* __restrict__ ws) {
    float nwh = 0.f, noff = 0.f, msum = 0.f;
    for (int t = threadIdx.x; t < BB * KOBJ; t += blockDim.x) {
        int b = t / KOBJ;
        float m = mask[t];
        int id = ind[t];
        const float* wp = wh_pred + (size_t)b * 2 * HW;
        const float* rp = reg_pred + (size_t)b * 2 * HW;
        float p0 = wp[id], p1 = wp[HW + id];
        float q0 = rp[id], q1 = rp[HW + id];
        float t0 = wh[t * 2], t1 = wh[t * 2 + 1];
        float r0 = reg[t * 2], r1 = reg[t * 2 + 1];
        nwh  += fabsf(p0 * m - t0 * m) + fabsf(p1 * m - t1 * m);
        noff += fabsf(q0 * m - r0 * m) + fabsf(q1 * m - r1 * m);
        msum += m;
    }
    __shared__ float sm[3][4];
    float a = wave_sum(nwh), b = wave_sum(noff), c = wave_sum(msum);
    int lane = threadIdx.x & 63, wid = threadIdx.x >> 6;
    if (lane == 0) { sm[0][wid] = a; sm[1][wid] = b; sm[2][wid] = c; }
    __syncthreads();
    if (threadIdx.x == 0) {
        float s0 = 0, s1 = 0, s2 = 0;
        for (int w = 0; w < 4; ++w) { s0 += sm[0][w]; s1 += sm[1][w]; s2 += sm[2][w]; }
        ws[3] = s0; ws[4] = s1; ws[5] = s2;   // single block: plain stores
    }
}

// ---------------- compaction of cls_id_map matches ----------------
__global__ void compact_kernel(const int* __restrict__ cmap,
                               int* __restrict__ cnt0, int* __restrict__ cnt1,
                               int* __restrict__ idx0, int* __restrict__ idx1, int n) {
    int stride = gridDim.x * blockDim.x;
    for (int i = blockIdx.x * blockDim.x + threadIdx.x; i < n; i += stride) {
        int v = cmap[i];
        if (v == 0) {
            int q = atomicAdd(cnt0, 1);
            if (q < KG) idx0[q] = i;
        } else if (v == 1) {
            int q = atomicAdd(cnt1, 1);
            if (q < KG) idx1[q] = i;
        }
    }
}

// ---------------- gather + L2-normalize embeddings into compact buffer ----------------
// grid: (Gx, 2) blocks of 128 threads; blockIdx.y = class
__global__ void gather_kernel(const float* __restrict__ id_pred,
                              const int*   __restrict__ cls_tr,
                              float* __restrict__ wsf,
                              float esc0, float esc1) {
    int cls = blockIdx.y;
    int* wsi = (int*)wsf;
    int cnt = wsi[8 + cls];
    int m = cnt < KG ? cnt : KG;
    const int* idxArr = wsi + 16 + cls * KG;
    int* tgtArr = wsi + 16 + 2 * KG + cls * KG;
    float* embArr = wsf + 16 + 4 * KG + (size_t)cls * KG * EMBD;
    float escale = cls ? esc1 : esc0;
    __shared__ float red[2];
    int tid = threadIdx.x;           // 128 threads, tid == channel
    for (int i = blockIdx.x; i < m; i += gridDim.x) {
        int p = idxArr[i];
        int b = p / HW, hw = p - b * HW;
        float f = id_pred[((size_t)b * EMBD + tid) * HW + hw];
        float ss = f * f;
        #pragma unroll
        for (int o = 32; o > 0; o >>= 1) ss += __shfl_down(ss, o, 64);
        if ((tid & 63) == 0) red[tid >> 6] = ss;
        __syncthreads();
        float s = red[0] + red[1];
        float scale = escale / fmaxf(sqrtf(s), 1e-12f);
        embArr[(size_t)i * EMBD + tid] = f * scale;
        if (tid == 0) tgtArr[i] = cls_tr[((size_t)b * 2 + cls) * HW + hw];
        __syncthreads();
    }
}

// ---------------- batched logits + online logsumexp + NLL ----------------
// grid: (KG/TE, 2) blocks of 256 threads; blockIdx.y = class
__global__ void reid_logits_kernel(const float* __restrict__ W0,
                                   const float* __restrict__ b0,
                                   const float* __restrict__ W1,
                                   const float* __restrict__ b1,
                                   float* __restrict__ wsf) {
    int cls = blockIdx.y;
    const int* wsi = (const int*)wsf;
    int cnt = wsi[8 + cls];
    int m = cnt < KG ? cnt : KG;
    int base = blockIdx.x * TE;
    if (base >= m) return;
    int nval = m - base; if (nval > TE) nval = TE;

    int nid = cls ? NID1 : NID0;
    const float* Wc = cls ? W1 : W0;
    const float* bc = cls ? b1 : b0;
    const float* embArr = wsf + 16 + 4 * KG + (size_t)cls * KG * EMBD;
    const int*   tgtArr = wsi + 16 + 2 * KG + cls * KG;
    float* nll_out = wsf + 6 + cls;

    __shared__ float emb_s[TE][EMBD];
    __shared__ float tgtl_s[TE];
    __shared__ int   tgt_s[TE];
    __shared__ float red_m[TE][4];
    __shared__ float red_se[TE][4];

    int tid = threadIdx.x;

    // load emb tile (zero-fill invalid entries to avoid NaN propagation)
    {
        const float4* src = (const float4*)(embArr + (size_t)base * EMBD);
        float4* dst = (float4*)&emb_s[0][0];
        int lim = nval * (EMBD / 4);
        for (int j = tid; j < TE * (EMBD / 4); j += 256)
            dst[j] = (j < lim) ? src[j] : make_float4(0.f, 0.f, 0.f, 0.f);
    }
    if (tid < TE) {
        tgt_s[tid]  = (tid < nval) ? tgtArr[base + tid] : -1;
        tgtl_s[tid] = 0.f;
    }
    __syncthreads();

    // each thread computes logits for rows r = tid, tid+256 against all TE embs
    float lg[2][TE];
    #pragma unroll
    for (int k = 0; k < 2; ++k)
        #pragma unroll
        for (int e = 0; e < TE; ++e) lg[k][e] = -1e30f;

    for (int k = 0; k < 2; ++k) {
        int r = tid + k * 256;
        if (r >= nid) break;
        const float4* wr = (const float4*)(Wc + (size_t)r * EMBD);
        float acc[TE];
        #pragma unroll
        for (int e = 0; e < TE; ++e) acc[e] = 0.f;
        #pragma unroll
        for (int j = 0; j < EMBD / 4; ++j) {
            float4 w = wr[j];
            #pragma unroll
            for (int e = 0; e < TE; ++e) {
                float4 em = ((const float4*)emb_s[e])[j];   // LDS broadcast
                acc[e] += w.x * em.x + w.y * em.y + w.z * em.z + w.w * em.w;
            }
        }
        float bias = bc[r];
        #pragma unroll
        for (int e = 0; e < TE; ++e) {
            float l = acc[e] + bias;
            lg[k][e] = l;
            if (r == tgt_s[e]) tgtl_s[e] = l;
        }
    }

    // per-thread (max, sumexp) per entry
    float mx[TE], se[TE];
    #pragma unroll
    for (int e = 0; e < TE; ++e) {
        float a = lg[0][e], b2 = lg[1][e];
        float M = fmaxf(a, b2);
        float s = expf(a - M) + expf(b2 - M);   // second term underflows if row absent
        if (tid >= nid) { M = -1e30f; s = 0.f; }
        mx[e] = M; se[e] = s;
    }

    // wave butterfly combine
    int lane = tid & 63, wid = tid >> 6;
    #pragma unroll
    for (int o = 32; o > 0; o >>= 1) {
        #pragma unroll
        for (int e = 0; e < TE; ++e) {
            float m2 = __shfl_down(mx[e], o, 64);
            float s2 = __shfl_down(se[e], o, 64);
            float M = fmaxf(mx[e], m2);
            float s = se[e] * expf(mx[e] - M) + s2 * expf(m2 - M);
            mx[e] = M; se[e] = s;
        }
    }
    if (lane == 0) {
        #pragma unroll
        for (int e = 0; e < TE; ++e) { red_m[e][wid] = mx[e]; red_se[e][wid] = se[e]; }
    }
    __syncthreads();

    // final combine: wave 0's 64 lanes = 16 entries × 4 wave-partials
    if (wid == 0) {
        int e = lane >> 2, w = lane & 3;
        float M = red_m[e][w], S = red_se[e][w];
        #pragma unroll
        for (int o = 1; o < 4; o <<= 1) {
            float m2 = __shfl_xor(M, o, 64);
            float s2 = __shfl_xor(S, o, 64);
            float Mn = fmaxf(M, m2);
            S = S * expf(M - Mn) + s2 * expf(m2 - Mn);
            M = Mn;
        }
        float nll = 0.f;
        if (w == 0 && e < nval) nll = M + logf(S) - tgtl_s[e];
        nll = wave_sum(nll);
        if (lane == 0) atomicAdd(nll_out, nll);
    }
}

// ---------------- final scalar combine ----------------
__global__ void final_kernel(const float* __restrict__ wsf,
                             const float* __restrict__ sdet,
                             const float* __restrict__ sid,
                             float* __restrict__ out) {
    if (threadIdx.x == 0 && blockIdx.x == 0) {
        const int* wsi = (const int*)wsf;
        float pos = wsf[0], neg = wsf[1], npos = wsf[2];
        float hm_loss = (npos > 0.f) ? -(pos + neg) / fmaxf(npos, 1.f) : -neg;
        float wh_loss  = wsf[3] / (wsf[5] * 2.f + 1e-4f);
        float off_loss = wsf[4] / (wsf[5] * 2.f + 1e-4f);
        float reid = 0.f;
        {
            int c0 = wsi[8];
            float nv = (float)(c0 < KG ? c0 : KG);
            float ce = wsf[6] / fmaxf(nv, 1.f);
            if (c0 > 0) reid += ce / fmaxf((float)c0, 1.f);
        }
        {
            int c1 = wsi[9];
            float nv = (float)(c1 < KG ? c1 : KG);
            float ce = wsf[7] / fmaxf(nv, 1.f);
            if (c1 > 0) reid += ce / fmaxf((float)c1, 1.f);
        }
        float det = 1.0f * hm_loss + 0.1f * wh_loss + 1.0f * off_loss;
        float sd = sdet[0], si = sid[0];
        float loss = 0.5f * (expf(-sd) * det + expf(-si) * reid + sd + si);
        out[0] = loss;
        out[1] = hm_loss;
        out[2] = wh_loss;
        out[3] = off_loss;
        out[4] = reid;
    }
}

extern "C" void kernel_launch(void* const* d_in, const int* in_sizes, int n_in,
                              void* d_out, int out_size, void* d_ws, size_t ws_size,
                              hipStream_t stream) {
    const float* hm_pred   = (const float*)d_in[0];
    const float* wh_pred   = (const float*)d_in[1];
    const float* reg_pred  = (const float*)d_in[2];
    const float* id_pred   = (const float*)d_in[3];
    const float* hm        = (const float*)d_in[4];
    const float* wh        = (const float*)d_in[5];
    const float* reg       = (const float*)d_in[6];
    const float* reg_mask  = (const float*)d_in[7];
    const int*   ind       = (const int*)d_in[8];
    const int*   cls_map   = (const int*)d_in[9];
    const int*   cls_tr    = (const int*)d_in[10];
    const float* W0        = (const float*)d_in[11];
    const float* b0        = (const float*)d_in[12];
    const float* W1        = (const float*)d_in[13];
    const float* b1        = (const float*)d_in[14];
    const float* s_det     = (const float*)d_in[15];
    const float* s_id      = (const float*)d_in[16];

    float* wsf = (float*)d_ws;
    int*   wsi = (int*)d_ws;
    int*   idx0 = wsi + 16;
    int*   idx1 = wsi + 16 + KG;

    // zero the 16-word accumulator header each call
    hipMemsetAsync(d_ws, 0, 64, stream);

    const int N1  = BB * HMC * HW;   // 661504, divisible by 4
    const int n4  = N1 / 4;
    const int NBH = BB * HW;         // 330752

    focal_kernel<<<(n4 + 255) / 256, 256, 0, stream>>>(
        (const float4*)hm_pred, (const float4*)hm, wsf, n4);

    reg_kernel<<<1, 256, 0, stream>>>(wh_pred, reg_pred, wh, reg, reg_mask, ind, wsf);

    compact_kernel<<<512, 256, 0, stream>>>(cls_map, wsi + 8, wsi + 9, idx0, idx1, NBH);

    const float esc0 = (float)(sqrt(2.0) * log((double)NID0 - 1.0));
    const float esc1 = (float)(sqrt(2.0) * log((double)NID1 - 1.0));

    gather_kernel<<<dim3(1024, 2), 128, 0, stream>>>(id_pred, cls_tr, wsf, esc0, esc1);

    reid_logits_kernel<<<dim3(KG / TE, 2), 256, 0, stream>>>(W0, b0, W1, b1, wsf);

    final_kernel<<<1, 64, 0, stream>>>(wsf, s_det, s_id, (float*)d_out);
}

// Round 3
// 87.121 us; speedup vs baseline: 9.2825x; 9.2825x over previous
//
#include <hip/hip_runtime.h>
#include <math.h>

// Problem constants (from reference)
#define BB    8
#define HMC   2
#define HW    41344           // 152*272
#define EMBD  128
#define KOBJ  128
#define KG    8192
#define NID0  500
#define NID1  300
#define TE    16              // entries per block in reid logits kernel

// d_ws layout (words):
//   [0] pos_loss [1] neg_loss [2] num_pos [3] num_wh [4] num_off [5] mask_sum
//   [6] nll0 [7] nll1  (float accumulators)
//   [8] cnt0 [9] cnt1  (int)   [10] done-counter (int)
//   [16 .. 16+KG)         idx0   [16+KG .. 16+2KG)  idx1
//   [16+2KG .. 16+3KG)    tgt0   [16+3KG .. 16+4KG) tgt1
//   [16+4KG ..)           emb0 (KG*128 f32), emb1 (KG*128 f32)

__device__ __forceinline__ float wave_sum(float v) {
    #pragma unroll
    for (int o = 32; o > 0; o >>= 1) v += __shfl_down(v, o, 64);
    return v;
}

// ---------------- fused: focal + compact + reg ----------------
__global__ void fused1_kernel(const float4* __restrict__ hp,
                              const float4* __restrict__ gt,
                              const int4*   __restrict__ cmap,
                              const float*  __restrict__ wh_pred,
                              const float*  __restrict__ reg_pred,
                              const float*  __restrict__ wh,
                              const float*  __restrict__ reg,
                              const float*  __restrict__ mask,
                              const int*    __restrict__ ind,
                              float* __restrict__ wsf, int n4, int nc4) {
    int* wsi = (int*)wsf;
    int tid = threadIdx.x;
    int gid = blockIdx.x * blockDim.x + tid;
    int gstride = gridDim.x * blockDim.x;

    __shared__ int stage0[1024], stage1[1024];   // grid=512 -> <=1024 elems/block
    __shared__ int lcnt0, lcnt1, gbase0, gbase1;
    __shared__ float sm[3][4];

    if (tid == 0) { lcnt0 = 0; lcnt1 = 0; }
    __syncthreads();

    // ---- compaction of cls_id_map matches (LDS staging, 2 global atomics/block) ----
    for (int i = gid; i < nc4; i += gstride) {
        int4 v = cmap[i];
        int b4 = i * 4;
        if (v.x == 0) stage0[atomicAdd(&lcnt0,1)] = b4+0; else if (v.x == 1) stage1[atomicAdd(&lcnt1,1)] = b4+0;
        if (v.y == 0) stage0[atomicAdd(&lcnt0,1)] = b4+1; else if (v.y == 1) stage1[atomicAdd(&lcnt1,1)] = b4+1;
        if (v.z == 0) stage0[atomicAdd(&lcnt0,1)] = b4+2; else if (v.z == 1) stage1[atomicAdd(&lcnt1,1)] = b4+2;
        if (v.w == 0) stage0[atomicAdd(&lcnt0,1)] = b4+3; else if (v.w == 1) stage1[atomicAdd(&lcnt1,1)] = b4+3;
    }
    __syncthreads();
    if (tid == 0) gbase0 = (lcnt0 > 0) ? atomicAdd(wsi + 8, lcnt0) : 0;
    if (tid == 1) gbase1 = (lcnt1 > 0) ? atomicAdd(wsi + 9, lcnt1) : 0;
    __syncthreads();
    for (int j = tid; j < lcnt0; j += blockDim.x) { int q = gbase0 + j; if (q < KG) wsi[16 + q] = stage0[j]; }
    for (int j = tid; j < lcnt1; j += blockDim.x) { int q = gbase1 + j; if (q < KG) wsi[16 + KG + q] = stage1[j]; }

    // ---- focal loss ----
    float pos = 0.f, neg = 0.f, cnt = 0.f;
    for (int i = gid; i < n4; i += gstride) {
        float4 x = hp[i];
        float4 g = gt[i];
        float xs[4] = {x.x, x.y, x.z, x.w};
        float gs[4] = {g.x, g.y, g.z, g.w};
        #pragma unroll
        for (int j = 0; j < 4; ++j) {
            float s = 1.f / (1.f + expf(-xs[j]));
            s = fminf(fmaxf(s, 1e-4f), 1.f - 1e-4f);
            float gv = gs[j];
            if (gv == 1.f) {
                float om = 1.f - s;
                pos += logf(s) * om * om;
                cnt += 1.f;
            } else {
                float nw = 1.f - gv; nw = nw * nw; nw = nw * nw;
                neg += logf(1.f - s) * s * s * nw;
            }
        }
    }
    {
        float a = wave_sum(pos), b = wave_sum(neg), c = wave_sum(cnt);
        int lane = tid & 63, wid = tid >> 6;
        if (lane == 0) { sm[0][wid] = a; sm[1][wid] = b; sm[2][wid] = c; }
        __syncthreads();
        if (tid == 0) {
            float s0 = 0, s1 = 0, s2 = 0;
            #pragma unroll
            for (int w = 0; w < 4; ++w) { s0 += sm[0][w]; s1 += sm[1][w]; s2 += sm[2][w]; }
            atomicAdd(wsf + 0, s0);
            atomicAdd(wsf + 1, s1);
            atomicAdd(wsf + 2, s2);
        }
    }

    // ---- wh / off L1 (block 0 only) ----
    if (blockIdx.x == 0) {
        __syncthreads();   // protect sm reuse
        float nwh = 0.f, noff = 0.f, msum = 0.f;
        for (int t = tid; t < BB * KOBJ; t += blockDim.x) {
            int b = t / KOBJ;
            float m = mask[t];
            int id = ind[t];
            const float* wp = wh_pred + (size_t)b * 2 * HW;
            const float* rp = reg_pred + (size_t)b * 2 * HW;
            float p0 = wp[id], p1 = wp[HW + id];
            float q0 = rp[id], q1 = rp[HW + id];
            float t0 = wh[t * 2], t1 = wh[t * 2 + 1];
            float r0 = reg[t * 2], r1 = reg[t * 2 + 1];
            nwh  += fabsf(p0 * m - t0 * m) + fabsf(p1 * m - t1 * m);
            noff += fabsf(q0 * m - r0 * m) + fabsf(q1 * m - r1 * m);
            msum += m;
        }
        float a = wave_sum(nwh), b = wave_sum(noff), c = wave_sum(msum);
        int lane = tid & 63, wid = tid >> 6;
        if (lane == 0) { sm[0][wid] = a; sm[1][wid] = b; sm[2][wid] = c; }
        __syncthreads();
        if (tid == 0) {
            float s0 = 0, s1 = 0, s2 = 0;
            #pragma unroll
            for (int w = 0; w < 4; ++w) { s0 += sm[0][w]; s1 += sm[1][w]; s2 += sm[2][w]; }
            wsf[3] = s0; wsf[4] = s1; wsf[5] = s2;
        }
    }
}

// ---------------- gather + L2-normalize embeddings ----------------
__global__ void gather_kernel(const float* __restrict__ id_pred,
                              const int*   __restrict__ cls_tr,
                              float* __restrict__ wsf,
                              float esc0, float esc1) {
    int cls = blockIdx.y;
    int* wsi = (int*)wsf;
    int cnt = wsi[8 + cls];
    int m = cnt < KG ? cnt : KG;
    const int* idxArr = wsi + 16 + cls * KG;
    int* tgtArr = wsi + 16 + 2 * KG + cls * KG;
    float* embArr = wsf + 16 + 4 * KG + (size_t)cls * KG * EMBD;
    float escale = cls ? esc1 : esc0;
    __shared__ float red[2];
    int tid = threadIdx.x;           // 128 threads, tid == channel
    for (int i = blockIdx.x; i < m; i += gridDim.x) {
        int p = idxArr[i];
        int b = p / HW, hw = p - b * HW;
        float f = id_pred[((size_t)b * EMBD + tid) * HW + hw];
        float ss = f * f;
        #pragma unroll
        for (int o = 32; o > 0; o >>= 1) ss += __shfl_down(ss, o, 64);
        if ((tid & 63) == 0) red[tid >> 6] = ss;
        __syncthreads();
        float s = red[0] + red[1];
        float scale = escale / fmaxf(sqrtf(s), 1e-12f);
        embArr[(size_t)i * EMBD + tid] = f * scale;
        if (tid == 0) tgtArr[i] = cls_tr[((size_t)b * 2 + cls) * HW + hw];
        __syncthreads();
    }
}

__device__ void final_combine(const float* wsf, float nll0, float nll1,
                              int c0, int c1,
                              const float* sdet, const float* sid,
                              float* out) {
    float pos = wsf[0], neg = wsf[1], npos = wsf[2];
    float hm_loss = (npos > 0.f) ? -(pos + neg) / fmaxf(npos, 1.f) : -neg;
    float wh_loss  = wsf[3] / (wsf[5] * 2.f + 1e-4f);
    float off_loss = wsf[4] / (wsf[5] * 2.f + 1e-4f);
    float reid = 0.f;
    if (c0 > 0) {
        float nv = (float)(c0 < KG ? c0 : KG);
        reid += (nll0 / fmaxf(nv, 1.f)) / fmaxf((float)c0, 1.f);
    }
    if (c1 > 0) {
        float nv = (float)(c1 < KG ? c1 : KG);
        reid += (nll1 / fmaxf(nv, 1.f)) / fmaxf((float)c1, 1.f);
    }
    float det = hm_loss + 0.1f * wh_loss + off_loss;
    float sd = sdet[0], si = sid[0];
    out[0] = 0.5f * (expf(-sd) * det + expf(-si) * reid + sd + si);
    out[1] = hm_loss;
    out[2] = wh_loss;
    out[3] = off_loss;
    out[4] = reid;
}

// ---------------- batched logits + logsumexp + NLL + fused final ----------------
// grid: (KG/TE, 2) x 256; blockIdx.y = class
__global__ __launch_bounds__(256)
void reid_logits_kernel(const float* __restrict__ W0, const float* __restrict__ b0,
                        const float* __restrict__ W1, const float* __restrict__ b1,
                        const float* __restrict__ sdet, const float* __restrict__ sid,
                        float* __restrict__ wsf, float* __restrict__ out) {
    int* wsi = (int*)wsf;
    int cls = blockIdx.y;
    int tid = threadIdx.x;

    int c0full = wsi[8], c1full = wsi[9];
    int m0 = c0full < KG ? c0full : KG;
    int m1 = c1full < KG ? c1full : KG;
    int a0 = (m0 + TE - 1) / TE, a1 = (m1 + TE - 1) / TE;
    int nact = a0 + a1;

    if (nact == 0) {   // degenerate: no matches at all
        if (blockIdx.x == 0 && cls == 0 && tid == 0)
            final_combine(wsf, 0.f, 0.f, c0full, c1full, sdet, sid, out);
        return;
    }
    int m = cls ? m1 : m0;
    int base = blockIdx.x * TE;
    if (base >= m) return;
    int nval = m - base; if (nval > TE) nval = TE;

    int nid = cls ? NID1 : NID0;
    const float* Wc = cls ? W1 : W0;
    const float* bc = cls ? b1 : b0;
    const float* embArr = wsf + 16 + 4 * KG + (size_t)cls * KG * EMBD;
    const int*   tgtArr = wsi + 16 + 2 * KG + cls * KG;

    __shared__ float emb_s[TE][EMBD];
    __shared__ int   tgt_s[TE];
    __shared__ float tgtl_s[TE];
    __shared__ float red_m[TE][4];
    __shared__ float red_s[TE][4];

    {   // load emb tile (zero-fill invalid)
        const float4* src = (const float4*)(embArr + (size_t)base * EMBD);
        float4* dst = (float4*)&emb_s[0][0];
        int lim = nval * (EMBD / 4);
        for (int j = tid; j < TE * (EMBD / 4); j += 256)
            dst[j] = (j < lim) ? src[j] : make_float4(0.f, 0.f, 0.f, 0.f);
    }
    if (tid < TE) { tgt_s[tid] = (tid < nval) ? tgtArr[base + tid] : -1; tgtl_s[tid] = 0.f; }
    __syncthreads();

    // rows r0 = tid (always < nid since nid >= 300 > 256), r1 = tid+256 (maybe invalid)
    int r0 = tid, r1 = tid + 256;
    bool v1ok = r1 < nid;
    const float4* wr0 = (const float4*)(Wc + (size_t)r0 * EMBD);
    const float4* wr1 = (const float4*)(Wc + (size_t)(v1ok ? r1 : 0) * EMBD);

    float acc0[TE], acc1[TE];
    #pragma unroll
    for (int e = 0; e < TE; ++e) { acc0[e] = 0.f; acc1[e] = 0.f; }

    for (int j = 0; j < EMBD / 4; ++j) {   // j never indexes a register array
        float4 w0 = wr0[j];
        float4 w1 = wr1[j];
        #pragma unroll
        for (int e = 0; e < TE; ++e) {
            float4 em = ((const float4*)emb_s[e])[j];   // wave-broadcast LDS read
            acc0[e] = fmaf(w0.x, em.x, fmaf(w0.y, em.y, fmaf(w0.z, em.z, fmaf(w0.w, em.w, acc0[e]))));
            acc1[e] = fmaf(w1.x, em.x, fmaf(w1.y, em.y, fmaf(w1.z, em.z, fmaf(w1.w, em.w, acc1[e]))));
        }
    }
    float bias0 = bc[r0];
    float bias1 = v1ok ? bc[r1] : 0.f;
    #pragma unroll
    for (int e = 0; e < TE; ++e) {
        acc0[e] += bias0;
        acc1[e] = v1ok ? (acc1[e] + bias1) : -1e30f;
        if (r0 == tgt_s[e]) tgtl_s[e] = acc0[e];
        if (v1ok && r1 == tgt_s[e]) tgtl_s[e] = acc1[e];
    }

    int lane = tid & 63, wid = tid >> 6;

    // pass 1: block max per entry (cheap fmax butterfly, no exp)
    float mx[TE];
    #pragma unroll
    for (int e = 0; e < TE; ++e) mx[e] = fmaxf(acc0[e], acc1[e]);
    #pragma unroll
    for (int o = 32; o > 0; o >>= 1) {
        #pragma unroll
        for (int e = 0; e < TE; ++e) mx[e] = fmaxf(mx[e], __shfl_xor(mx[e], o, 64));
    }
    if (lane == 0) {
        #pragma unroll
        for (int e = 0; e < TE; ++e) red_m[e][wid] = mx[e];
    }
    __syncthreads();
    float bm[TE];
    #pragma unroll
    for (int e = 0; e < TE; ++e)
        bm[e] = fmaxf(fmaxf(red_m[e][0], red_m[e][1]), fmaxf(red_m[e][2], red_m[e][3]));

    // pass 2: sum of exps (2 expf per entry per thread)
    float se[TE];
    #pragma unroll
    for (int e = 0; e < TE; ++e) se[e] = expf(acc0[e] - bm[e]) + expf(acc1[e] - bm[e]);
    #pragma unroll
    for (int o = 32; o > 0; o >>= 1) {
        #pragma unroll
        for (int e = 0; e < TE; ++e) se[e] += __shfl_xor(se[e], o, 64);
    }
    if (lane == 0) {
        #pragma unroll
        for (int e = 0; e < TE; ++e) red_s[e][wid] = se[e];
    }
    __syncthreads();

    if (tid == 0) {
        float nll = 0.f;
        #pragma unroll
        for (int e = 0; e < TE; ++e) {
            if (e < nval) {
                float S = red_s[e][0] + red_s[e][1] + red_s[e][2] + red_s[e][3];
                nll += bm[e] + logf(S) - tgtl_s[e];
            }
        }
        atomicAdd(wsf + 6 + cls, nll);
        __threadfence();
        int old = atomicAdd(wsi + 10, 1);
        if (old == nact - 1) {   // last active block: fused final combine
            float nll0 = atomicAdd(wsf + 6, 0.f);   // coherent atomic read
            float nll1 = atomicAdd(wsf + 7, 0.f);
            final_combine(wsf, nll0, nll1, c0full, c1full, sdet, sid, out);
        }
    }
}

extern "C" void kernel_launch(void* const* d_in, const int* in_sizes, int n_in,
                              void* d_out, int out_size, void* d_ws, size_t ws_size,
                              hipStream_t stream) {
    const float* hm_pred   = (const float*)d_in[0];
    const float* wh_pred   = (const float*)d_in[1];
    const float* reg_pred  = (const float*)d_in[2];
    const float* id_pred   = (const float*)d_in[3];
    const float* hm        = (const float*)d_in[4];
    const float* wh        = (const float*)d_in[5];
    const float* reg       = (const float*)d_in[6];
    const float* reg_mask  = (const float*)d_in[7];
    const int*   ind       = (const int*)d_in[8];
    const int*   cls_map   = (const int*)d_in[9];
    const int*   cls_tr    = (const int*)d_in[10];
    const float* W0        = (const float*)d_in[11];
    const float* b0        = (const float*)d_in[12];
    const float* W1        = (const float*)d_in[13];
    const float* b1        = (const float*)d_in[14];
    const float* s_det     = (const float*)d_in[15];
    const float* s_id      = (const float*)d_in[16];

    float* wsf = (float*)d_ws;

    // zero the 16-word accumulator header (incl. done-counter) each call
    hipMemsetAsync(d_ws, 0, 64, stream);

    const int n4  = (BB * HMC * HW) / 4;   // 165376
    const int nc4 = (BB * HW) / 4;         // 82688

    fused1_kernel<<<512, 256, 0, stream>>>(
        (const float4*)hm_pred, (const float4*)hm, (const int4*)cls_map,
        wh_pred, reg_pred, wh, reg, reg_mask, ind, wsf, n4, nc4);

    const float esc0 = (float)(sqrt(2.0) * log((double)NID0 - 1.0));
    const float esc1 = (float)(sqrt(2.0) * log((double)NID1 - 1.0));

    gather_kernel<<<dim3(1024, 2), 128, 0, stream>>>(id_pred, cls_tr, wsf, esc0, esc1);

    reid_logits_kernel<<<dim3(KG / TE, 2), 256, 0, stream>>>(
        W0, b0, W1, b1, s_det, s_id, wsf, (float*)d_out);
}